// Round 1
// baseline (237.747 us; speedup 1.0000x reference)
//
#include <hip/hip_runtime.h>
#include <cmath>
#include <complex>
#include <algorithm>

#define CAP_S 512   // max edges out of Co (Poisson(12) max over 50k nodes ~35)
#define CAP_T 512   // max distinct targets of Co's edges

// ====================== host-side Wigner 3j (exact port, runs at .so load) =====================
namespace w3jhost {
static double fact(int n){
  static const double f[13]={1,1,2,6,24,120,720,5040,40320,362880,3628800,39916800,479001600};
  return f[n];
}
static double su2_cg(int j1,int m1,int j2,int m2,int j3,int m3){
  if(m3!=m1+m2) return 0.0;
  int vmin = std::max(std::max(-j1+j2+m3,-j1+m1),0);
  int vmax = std::min(std::min(j2+j3+m1, j3-j1+j2), j3+m3);
  double C = std::sqrt((double)(2*j3+1)*fact(j3+j1-j2)*fact(j3-j1+j2)*fact(j1+j2-j3)*fact(j3+m3)*fact(j3-m3)
            /(fact(j1+j2+j3+1)*fact(j1-m1)*fact(j1+m1)*fact(j2-m2)*fact(j2+m2)));
  double S=0.0;
  for(int v=vmin;v<=vmax;v++){
    double sgn = ((v+j2+m2)&1)?-1.0:1.0;
    S += sgn/fact(v)*fact(j2+j3+m1-v)*fact(j1-m1+v)/fact(j3-j1+j2-v)/fact(j3+m3-v)/fact(v+j1-j2-m3);
  }
  return C*S;
}
static void real_basis(int l, std::complex<double> q[7][7]){
  for(int i=0;i<7;i++)for(int j=0;j<7;j++) q[i][j]=0.0;
  const double r = std::sqrt(0.5);
  for(int m=-l;m<0;m++){ q[l+m][l-m]=r; q[l+m][l+m]=std::complex<double>(0.0,-r); }
  q[l][l]=1.0;
  for(int m=1;m<=l;m++){ double sg=(m&1)?-1.0:1.0; q[l+m][l+m]=sg*r; q[l+m][l-m]=std::complex<double>(0.0,sg*r); }
  std::complex<double> f;
  switch(l&3){ case 0: f={1,0};break; case 1: f={0,-1};break; case 2: f={-1,0};break; default: f={0,1};break; }
  for(int i=0;i<7;i++)for(int j=0;j<7;j++) q[i][j]*=f;
}
} // namespace w3jhost

struct W3JArg { float w[675]; };  // 7 paths concatenated, layout [i*(2l2+1)+j]*5+k

static W3JArg compute_w3j(){
  using namespace w3jhost;
  W3JArg out{};
  const int pl1[7]={0,1,1,2,2,3,3}, pl2[7]={2,1,3,0,2,1,3};
  int off=0;
  for(int p=0;p<7;p++){
    int l1=pl1[p], l2=pl2[p], l3=2;
    int n1=2*l1+1, n2=2*l2+1, n3=2*l3+1;
    double C[7][7][5];
    for(int i=0;i<7;i++)for(int k=0;k<7;k++)for(int n=0;n<5;n++) C[i][k][n]=0.0;
    for(int m1=-l1;m1<=l1;m1++)for(int m2=-l2;m2<=l2;m2++)
      if(std::abs(m1+m2)<=l3) C[l1+m1][l2+m2][l3+m1+m2]=su2_cg(l1,m1,l2,m2,l3,m1+m2);
    std::complex<double> Q1[7][7],Q2[7][7],Q3[7][7];
    real_basis(l1,Q1); real_basis(l2,Q2); real_basis(l3,Q3);
    double Cr[7][7][5]; double nrm=0.0;
    for(int a=0;a<n1;a++)for(int b=0;b<n2;b++)for(int c=0;c<n3;c++){
      std::complex<double> s(0.0,0.0);
      for(int i=0;i<n1;i++)for(int k=0;k<n2;k++)for(int n=0;n<n3;n++){
        double cv=C[i][k][n]; if(cv==0.0) continue;
        s += Q1[i][a]*Q2[k][b]*std::conj(Q3[n][c])*cv;  // einsum 'ij,kl,mn,ikn->jlm'
      }
      Cr[a][b][c]=s.real(); nrm+=s.real()*s.real();
    }
    nrm=std::sqrt(nrm);
    for(int a=0;a<n1;a++)for(int b=0;b<n2;b++)for(int c=0;c<n3;c++)
      out.w[off+(a*n2+b)*n3+c]=(float)(Cr[a][b][c]/nrm);
    off+=n1*n2*n3;
  }
  return out;
}
static const W3JArg g_w3j = compute_w3j();  // constant data; same every call

// ====================== device helpers ======================
__device__ __forceinline__ void calc_sh(float x,float y,float z,float* sh){
  float x2=x*x,y2=y*y,z2=z*z;
  const float s3=1.7320508075688772f, s5=2.2360679774997896f, s15=3.872983346207417f;
  const float s70_4=2.091650066335189f, s105=10.246950765959598f, s42_4=1.6201851746019651f;
  const float s7_2=1.3228756555322954f, s105_2=5.123475382979799f;
  sh[0]=1.f;
  sh[1]=s3*x; sh[2]=s3*y; sh[3]=s3*z;
  sh[4]=s15*x*z; sh[5]=s15*x*y; sh[6]=s5*(y2-0.5f*(x2+z2)); sh[7]=s15*y*z; sh[8]=0.5f*s15*(z2-x2);
  sh[9]=s70_4*x*(3.f*z2-x2); sh[10]=s105*x*y*z; sh[11]=s42_4*x*(5.f*y2-1.f);
  sh[12]=s7_2*y*(5.f*y2-3.f); sh[13]=s42_4*z*(5.f*y2-1.f); sh[14]=s105_2*y*(z2-x2); sh[15]=s70_4*z*(z2-3.f*x2);
}

// ====================== kernels ======================
__global__ void k_bincount(const int* __restrict__ eto, int E, int* __restrict__ counts){
  int e=blockIdx.x*blockDim.x+threadIdx.x;
  if(e<E) atomicAdd(&counts[eto[e]],1);
}

__global__ void k_argmax(const int* __restrict__ counts, int N, unsigned long long* __restrict__ packed){
  __shared__ unsigned long long sm;
  if(threadIdx.x==0) sm=0ull;
  __syncthreads();
  int i=blockIdx.x*blockDim.x+threadIdx.x;
  unsigned long long v=0ull;
  if(i<N)
    v=(((unsigned long long)(unsigned)counts[i])<<32) | (unsigned long long)(0xFFFFFFFFu-(unsigned)i);
  atomicMax(&sm,v);
  __syncthreads();
  if(threadIdx.x==0) atomicMax(packed,sm);
}

__global__ void k_collect(const int* __restrict__ efrom, const int* __restrict__ eto, int E,
                          const unsigned long long* __restrict__ packed,
                          int* __restrict__ S, int* __restrict__ numS, int* __restrict__ flagslot){
  int e=blockIdx.x*blockDim.x+threadIdx.x;
  if(e>=E) return;
  int co=(int)(0xFFFFFFFFu-(unsigned)((*packed)&0xFFFFFFFFull));  // numpy argmax (first max)
  if(efrom[e]==co){
    int p=atomicAdd(numS,1);
    if(p<CAP_S) S[p]=e;
    flagslot[eto[e]]=1;   // racing identical stores: fine
  }
}

__global__ void k_slots(int* __restrict__ flagslot, int N, int* __restrict__ numT){
  int v=blockIdx.x*blockDim.x+threadIdx.x;
  if(v>=N) return;
  if(flagslot[v]==1){
    int s=atomicAdd(numT,1);
    flagslot[v]=(s<CAP_T)?(s+2):0;
  }
}

// full per-edge pipeline (sh + radial MLP + mid), accumulated into node_mid for flagged source nodes
__global__ void k_mid(const float* __restrict__ x, const float* __restrict__ pos,
                      const int* __restrict__ efrom, const int* __restrict__ eto,
                      const float* __restrict__ W1, const float* __restrict__ W2,
                      int E, const int* __restrict__ flagslot, float* __restrict__ node_mid){
  int e=blockIdx.x*blockDim.x+threadIdx.x;
  if(e>=E) return;
  int a=efrom[e];
  int fs=flagslot[a];
  if(fs<2) return;        // ~144 of 600k threads survive
  int b=eto[e];
  float dx=pos[3*b]-pos[3*a], dy=pos[3*b+1]-pos[3*a+1], dz=pos[3*b+2]-pos[3*a+2];
  float d=sqrtf(dx*dx+dy*dy+dz*dz);
  float inv=1.f/d;
  float sh[16]; calc_sh(dx*inv,dy*inv,dz*inv,sh);
  // soft_one_hot radial embedding
  float emb[20];
  const float step=3.5f/21.f;
  const float pref=(float)(1.14136*7.3890560989306495);  // 1.14136*e^2
  for(int i=0;i<20;i++){
    float t=(d-(float)(i+1)*step)/step;
    float A=t+1.f, B=1.f-t;
    float ua=(A>0.f)?expf(-1.f/A):0.f;
    float ub=(B>0.f)?expf(-1.f/B):0.f;
    emb[i]=pref*ua*ub;
  }
  // MLP: h = 1.679177 * silu(emb@W1/sqrt(20)); tw = h@W2/sqrt(30)
  float h[30];
  for(int j=0;j<30;j++){
    float z=0.f;
    for(int i=0;i<20;i++) z+=emb[i]*W1[i*30+j];
    z*=0.22360679774997896f;
    h[j]=1.679177f*z/(1.f+expf(-z));
  }
  float tw[20];
  for(int c=0;c<20;c++){
    float t=0.f;
    for(int j=0;j<30;j++) t+=h[j]*W2[j*20+c];
    tw[c]=t*0.18257418583505536f;
  }
  float s=x[b];
  float* nm=node_mid+(size_t)(fs-2)*80;
  const int offs[4]={0,5,20,45}, shoff[4]={0,1,4,9};
  const float isq6=0.4082482904638631f;  // 1/sqrt(num_neighbors)
  for(int l=0;l<4;l++){
    int w=2*l+1;
    for(int u=0;u<5;u++){
      float cfac=s*tw[l*5+u]*isq6;
      for(int mm=0;mm<w;mm++)
        atomicAdd(&nm[offs[l]+u*w+mm], cfac*sh[shoff[l]+mm]);
    }
  }
}

// second tensor product for edges out of Co only, reduced to the 5 output floats
__global__ void k_final(const float* __restrict__ pos, const int* __restrict__ efrom,
                        const int* __restrict__ eto, const float* __restrict__ tp2,
                        const int* __restrict__ flagslot, const float* __restrict__ node_mid,
                        const int* __restrict__ S, const int* __restrict__ numS,
                        W3JArg w3, float* __restrict__ out5){
  __shared__ float acc[5];
  if(threadIdx.x<5) acc[threadIdx.x]=0.f;
  __syncthreads();
  int ns=*numS; if(ns>CAP_S) ns=CAP_S;
  const int pl1[7]={0,1,1,2,2,3,3}, pl2[7]={2,1,3,0,2,1,3};
  const int wbase[7]={0,25,70,175,200,325,430};
  const int offs[4]={0,5,20,45}, shoff[4]={0,1,4,9};
  for(int t=threadIdx.x;t<ns;t+=blockDim.x){
    int e=S[t];
    int a=efrom[e], b=eto[e];
    int fs=flagslot[b];
    if(fs<2) continue;
    const float* m=node_mid+(size_t)(fs-2)*80;
    float dx=pos[3*b]-pos[3*a], dy=pos[3*b+1]-pos[3*a+1], dz=pos[3*b+2]-pos[3*a+2];
    float d=sqrtf(dx*dx+dy*dy+dz*dz), inv=1.f/d;
    float sh[16]; calc_sh(dx*inv,dy*inv,dz*inv,sh);
    float o[5]={0.f,0.f,0.f,0.f,0.f};
    for(int p=0;p<7;p++){
      int l1=pl1[p], l2=pl2[p];
      int n1=2*l1+1, n2=2*l2+1;
      const float* W=w3.w+wbase[p];
      for(int u=0;u<5;u++){
        float tu=tp2[p*5+u];
        for(int i=0;i<n1;i++){
          float mi=m[offs[l1]+u*n1+i]*tu;
          for(int j=0;j<n2;j++){
            float c=mi*sh[shoff[l2]+j];
            const float* Wk=W+(i*n2+j)*5;
            for(int k=0;k<5;k++) o[k]+=Wk[k]*c;
          }
        }
      }
    }
    for(int k=0;k<5;k++) atomicAdd(&acc[k],o[k]);
  }
  __syncthreads();
  const float scale=0.37796447300922725f*0.4082482904638631f;  // ALPHA2 * 1/sqrt(6)
  if(threadIdx.x<5) out5[threadIdx.x]=acc[threadIdx.x]*scale;
}

// ====================== launch ======================
extern "C" void kernel_launch(void* const* d_in, const int* in_sizes, int n_in,
                              void* d_out, int out_size, void* d_ws, size_t ws_size,
                              hipStream_t stream){
  const float* x    =(const float*)d_in[0];
  const float* pos  =(const float*)d_in[1];
  const int*   efrom=(const int*)  d_in[2];
  const int*   eto  =(const int*)  d_in[3];
  const float* W1   =(const float*)d_in[4];
  const float* W2   =(const float*)d_in[5];
  const float* tp2  =(const float*)d_in[6];
  int N=in_sizes[0], E=in_sizes[2];

  char* ws=(char*)d_ws;
  size_t o=0;
  int* counts=(int*)(ws+o);                 o+=(size_t)N*4;
  int* flagslot=(int*)(ws+o);               o+=(size_t)N*4;
  o=(o+15)&~(size_t)15;
  unsigned long long* packed=(unsigned long long*)(ws+o); o+=8;
  int* numS=(int*)(ws+o);                   o+=4;
  int* numT=(int*)(ws+o);                   o+=4;
  o=(o+15)&~(size_t)15;
  int* S=(int*)(ws+o);                      o+=(size_t)CAP_S*4;
  float* node_mid=(float*)(ws+o);           o+=(size_t)CAP_T*80*4;

  hipMemsetAsync(d_ws,0,o,stream);  // ws is re-poisoned 0xAA before every call

  const int tb=256;
  int gE=(E+tb-1)/tb, gN=(N+tb-1)/tb;
  k_bincount<<<gE,tb,0,stream>>>(eto,E,counts);
  k_argmax  <<<gN,tb,0,stream>>>(counts,N,packed);
  k_collect <<<gE,tb,0,stream>>>(efrom,eto,E,packed,S,numS,flagslot);
  k_slots   <<<gN,tb,0,stream>>>(flagslot,N,numT);
  k_mid     <<<gE,tb,0,stream>>>(x,pos,efrom,eto,W1,W2,E,flagslot,node_mid);
  k_final   <<<1,64,0,stream>>>(pos,efrom,eto,tp2,flagslot,node_mid,S,numS,g_w3j,(float*)d_out);
}